// Round 12
// baseline (341.027 us; speedup 1.0000x reference)
//
#include <hip/hip_runtime.h>
#include <hip/hip_bf16.h>

typedef __attribute__((ext_vector_type(8))) short short8;   // 8 bf16 (4 VGPRs)
typedef __attribute__((ext_vector_type(4))) float f32x4;    // MFMA 16x16 C/D
typedef __attribute__((ext_vector_type(16))) float f32x16;  // MFMA 32x32 C/D

#define NB 8
#define NC 256
#define NN 4096
#define ND 32
#define NCH 16   // j-chunks of 256
#define LOG2E 1.44269504088896340736f

// P tile [2][128][256] ushort, 16B-slot XOR swizzle. row<<8 + (col^((row&15)<<3))
#define PIDX(row, col) (((row) << 8) + ((col) ^ (((row) & 15) << 3)))

static __device__ __forceinline__ ushort f2bf(float f) {
  __hip_bfloat16 h = __float2bfloat16(f);
  return reinterpret_cast<ushort&>(h);
}

// ---------------------------------------------------------------------------
// Projection (unchanged): fp32 MAC, bf16 out; Q pre-scaled by log2(e).
//   blockIdx.y==0 : o in [0,64)  -> QK[b][n][64]  (q 0..31, k 32..63)
//   blockIdx.y>=1 : o in [64,320)-> Vt[b][o-64][n]  (V transposed, bf16)
// ---------------------------------------------------------------------------
__global__ __launch_bounds__(256, 4)
void proj_kernel(const float* __restrict__ x,
                 const float* __restrict__ wq, const float* __restrict__ bq,
                 const float* __restrict__ wk, const float* __restrict__ bk,
                 const float* __restrict__ wv, const float* __restrict__ bv,
                 ushort* __restrict__ qk, ushort* __restrict__ vt) {
  __shared__ float Xs[16][128];
  __shared__ float Ws[16][64];
  const int n0 = blockIdx.x * 128;
  const int o0 = blockIdx.y * 64;
  const int b  = blockIdx.z;
  const int t  = threadIdx.x;
  const int og4 = t & 15;
  const int ng  = t >> 4;

  float acc[4][8];
#pragma unroll
  for (int i = 0; i < 4; ++i)
#pragma unroll
    for (int j = 0; j < 8; ++j) acc[i][j] = 0.f;

  const int xs_r = t >> 4;
  const int xs_c = (t & 15) * 4;
  const int ws_o = t & 63;
  const int ws_c = (t >> 6) * 4;
  const float* wrow;
  {
    const int o = o0 + ws_o;
    if (o < 32)      wrow = wq + (size_t)o * NC;
    else if (o < 64) wrow = wk + (size_t)(o - 32) * NC;
    else             wrow = wv + (size_t)(o - 64) * NC;
  }

  for (int c0 = 0; c0 < NC; c0 += 16) {
    __syncthreads();
    const float* xsrc = x + ((size_t)(b * NC + c0 + xs_r)) * NN + n0;
    *(float4*)&Xs[xs_r][xs_c]      = *(const float4*)(xsrc + xs_c);
    *(float4*)&Xs[xs_r][64 + xs_c] = *(const float4*)(xsrc + 64 + xs_c);
    {
      const float4 wv4 = *(const float4*)(wrow + c0 + ws_c);
      Ws[ws_c + 0][ws_o] = wv4.x;
      Ws[ws_c + 1][ws_o] = wv4.y;
      Ws[ws_c + 2][ws_o] = wv4.z;
      Ws[ws_c + 3][ws_o] = wv4.w;
    }
    __syncthreads();
#pragma unroll
    for (int cc = 0; cc < 16; ++cc) {
      const float4 wv4 = *(const float4*)&Ws[cc][og4 * 4];
      const float4 xa  = *(const float4*)&Xs[cc][ng * 8];
      const float4 xb  = *(const float4*)&Xs[cc][ng * 8 + 4];
      const float wvv[4] = {wv4.x, wv4.y, wv4.z, wv4.w};
      const float xaa[8] = {xa.x, xa.y, xa.z, xa.w, xb.x, xb.y, xb.z, xb.w};
#pragma unroll
      for (int i = 0; i < 4; ++i)
#pragma unroll
        for (int j = 0; j < 8; ++j) acc[i][j] += wvv[i] * xaa[j];
    }
  }

  if (blockIdx.y == 0) {
    float bb[4], sc[4];
#pragma unroll
    for (int i = 0; i < 4; ++i) {
      const int o = og4 * 4 + i;
      bb[i] = (o < 32) ? bq[o] : bk[o - 32];
      sc[i] = (o < 32) ? LOG2E : 1.0f;
    }
#pragma unroll
    for (int j = 0; j < 8; ++j) {
      union { ushort u[4]; uint2 v; } pk;
#pragma unroll
      for (int i = 0; i < 4; ++i) pk.u[i] = f2bf((acc[i][j] + bb[i]) * sc[i]);
      *(uint2*)(qk + ((size_t)(b * NN + n0 + ng * 8 + j)) * 64 + og4 * 4) = pk.v;
    }
  } else {
#pragma unroll
    for (int i = 0; i < 4; ++i) {
      const int c = o0 - 64 + og4 * 4 + i;
      const float bb = bv[c];
      union { ushort u[8]; uint4 v; } pk;
#pragma unroll
      for (int j = 0; j < 8; ++j) pk.u[j] = f2bf(acc[i][j] + bb);
      *(uint4*)(vt + ((size_t)(b * NC + c)) * NN + n0 + ng * 8) = pk.v;
    }
  }
}

// ---------------------------------------------------------------------------
// Flash attention, producer/consumer (R10 base) + register-funded pipelining.
// 256 blocks x 512 threads. Block = (b, 128 q-rows). j-chunk 256, 17
// intervals, ONE barrier each. P double-buffered (swizzled, 128 KB).
//  Waves 0-3 (S): rows w*32..+32: swapped mfma16(K,Q), exp2, packed b64 P
//    writes into P[iv&1]. K cross-chunk double-buffered in regs (kfA/kfB,
//    16 frags each): chunk iv+1's 16 loads issued BEFORE computing chunk iv.
//  Waves 4-7 (PV): consume P[(iv-1)&1]: 32x32x16 MFMA, 64 ch/wave
//    (OA/OB = 128 AGPR), V ping-pong prefetched in groups of 2 ji.
// launch_bounds(512,1): 2 waves/SIMD with per-SIMD file 2048 regs -> up to
// ~1024 regs/wave available; no spill at ~300 total (R9 spilled because
// (512,2) capped static at 128).
// ---------------------------------------------------------------------------
#define S_BODY(IV, KCUR, KNXT)                                                \
  do {                                                                        \
    ushort* Pb = P[(IV) & 1];                                                 \
    if ((IV) + 1 < NCH) {                                                     \
      const ushort* kn = kbase + (size_t)((IV) + 1) * 256 * 64;               \
      _Pragma("unroll")                                                       \
      for (int jt = 0; jt < 16; ++jt)                                         \
        KNXT[jt] = *(const short8*)(kn + (size_t)(jt * 16 + c16) * 64);       \
    }                                                                         \
    _Pragma("unroll")                                                         \
    for (int jt = 0; jt < 16; ++jt) {                                         \
      const f32x4 s0 = __builtin_amdgcn_mfma_f32_16x16x32_bf16(               \
          KCUR[jt], qf0, zero, 0, 0, 0);                                      \
      const f32x4 s1 = __builtin_amdgcn_mfma_f32_16x16x32_bf16(               \
          KCUR[jt], qf1, zero, 0, 0, 0);                                      \
      union { ushort u[4]; uint2 v; } pk0, pk1;                               \
      _Pragma("unroll")                                                       \
      for (int r = 0; r < 4; ++r) {                                           \
        const float e0 = exp2f(s0[r]);                                        \
        const float e1 = exp2f(s1[r]);                                        \
        lp0 += e0; lp1 += e1;                                                 \
        pk0.u[r] = f2bf(e0); pk1.u[r] = f2bf(e1);                             \
      }                                                                       \
      const int col = jt * 16 + g16 * 4;                                      \
      *(uint2*)&Pb[PIDX(prow0, col)] = pk0.v;                                 \
      *(uint2*)&Pb[PIDX(prow1, col)] = pk1.v;                                 \
    }                                                                         \
  } while (0)

#define PV_LOADG(VSET, J0, G)                                                 \
  do {                                                                        \
    VSET[0] = *(const short8*)(vbA + (J0) + (G) * 32);                        \
    VSET[1] = *(const short8*)(vbB + (J0) + (G) * 32);                        \
    VSET[2] = *(const short8*)(vbA + (J0) + (G) * 32 + 16);                   \
    VSET[3] = *(const short8*)(vbB + (J0) + (G) * 32 + 16);                   \
  } while (0)

#define PV_COMPG(VSET, Pb, J0, G)                                             \
  do {                                                                        \
    _Pragma("unroll")                                                         \
    for (int k = 0; k < 2; ++k) {                                             \
      const int jo = (G) * 32 + k * 16;                                       \
      _Pragma("unroll")                                                       \
      for (int isub = 0; isub < 4; ++isub) {                                  \
        const short8 pa =                                                     \
            *(const short8*)&Pb[PIDX(isub * 32 + c32, jo + l5 * 8)];          \
        OA[isub] = __builtin_amdgcn_mfma_f32_32x32x16_bf16(                   \
            pa, VSET[k * 2], OA[isub], 0, 0, 0);                              \
        OB[isub] = __builtin_amdgcn_mfma_f32_32x32x16_bf16(                   \
            pa, VSET[k * 2 + 1], OB[isub], 0, 0, 0);                          \
      }                                                                       \
    }                                                                         \
  } while (0)

#define PV_BODY(IV)                                                           \
  do {                                                                        \
    const int ch = (IV) - 1;                                                  \
    const ushort* Pb = P[ch & 1];                                             \
    const int j0 = ch * 256;                                                  \
    short8 vA[4], vB[4];                                                      \
    PV_LOADG(vA, j0, 0);                                                      \
    __builtin_amdgcn_s_setprio(1);                                            \
    PV_LOADG(vB, j0, 1);  PV_COMPG(vA, Pb, j0, 0);                            \
    PV_LOADG(vA, j0, 2);  PV_COMPG(vB, Pb, j0, 1);                            \
    PV_LOADG(vB, j0, 3);  PV_COMPG(vA, Pb, j0, 2);                            \
    PV_LOADG(vA, j0, 4);  PV_COMPG(vB, Pb, j0, 3);                            \
    PV_LOADG(vB, j0, 5);  PV_COMPG(vA, Pb, j0, 4);                            \
    PV_LOADG(vA, j0, 6);  PV_COMPG(vB, Pb, j0, 5);                            \
    PV_LOADG(vB, j0, 7);  PV_COMPG(vA, Pb, j0, 6);                            \
    PV_COMPG(vB, Pb, j0, 7);                                                  \
    __builtin_amdgcn_s_setprio(0);                                            \
  } while (0)

__global__ __launch_bounds__(512, 1)
void attn_kernel(const ushort* __restrict__ qk, const ushort* __restrict__ vt,
                 const float* __restrict__ x, const float* __restrict__ gamma,
                 float* __restrict__ out) {
  __shared__ __align__(16) ushort P[2][128 * 256];   // 128 KB, swizzled
  __shared__ __align__(16) float lL[128];

  const int lin  = blockIdx.x;
  const int b    = lin & 7;              // XCD swizzle: batch per XCD L2
  const int i0   = (lin >> 3) * 128;
  const int t    = threadIdx.x;
  const int w    = t >> 6;               // 0..7
  const int lane = t & 63;
  const int g16  = lane >> 4;
  const int c16  = lane & 15;
  const int l5   = lane >> 5;
  const int c32  = lane & 31;

  const f32x4 zero = {0.f, 0.f, 0.f, 0.f};
  const bool isS = (w < 4);

  // ---- S state (waves 0-3): 32 q-rows each ----
  const int prow0 = w * 32 + c16;
  const int prow1 = prow0 + 16;
  short8 qf0, qf1;
  short8 kfA[16], kfB[16];
  float lp0 = 0.f, lp1 = 0.f;
  const ushort* kbase = qk + ((size_t)b * NN) * 64 + 32 + g16 * 8;
  if (isS) {
    qf0 = *(const short8*)(qk + ((size_t)(b * NN + i0 + prow0)) * 64 + g16 * 8);
    qf1 = *(const short8*)(qk + ((size_t)(b * NN + i0 + prow1)) * 64 + g16 * 8);
    // prologue: chunk 0 into kfA
#pragma unroll
    for (int jt = 0; jt < 16; ++jt)
      kfA[jt] = *(const short8*)(kbase + (size_t)(jt * 16 + c16) * 64);
  }

  // ---- PV state (waves 4-7): 64 channels each ----
  const int p = w - 4;
  f32x16 OA[4], OB[4];
  const ushort* vbA = nullptr; const ushort* vbB = nullptr;
  if (!isS) {
#pragma unroll
    for (int isub = 0; isub < 4; ++isub)
#pragma unroll
      for (int e = 0; e < 16; ++e) { OA[isub][e] = 0.f; OB[isub][e] = 0.f; }
    vbA = vt + ((size_t)(b * NC + p * 64 + c32)) * NN + l5 * 8;
    vbB = vt + ((size_t)(b * NC + p * 64 + 32 + c32)) * NN + l5 * 8;
  }

  // 17 intervals: iv loop unrolled x2 for static kfA/kfB ping-pong
  for (int iv2 = 0; iv2 < NCH; iv2 += 2) {
    if (isS) S_BODY(iv2, kfA, kfB);
    else if (iv2 >= 1) PV_BODY(iv2);
    __syncthreads();
    if (isS) S_BODY(iv2 + 1, kfB, kfA);
    else PV_BODY(iv2 + 1);
    __syncthreads();
  }
  // interval 16: S finalizes row sums; PV consumes chunk 15
  if (isS) {
    lp0 += __shfl_xor(lp0, 16); lp0 += __shfl_xor(lp0, 32);
    lp1 += __shfl_xor(lp1, 16); lp1 += __shfl_xor(lp1, 32);
    if (g16 == 0) { lL[prow0] = lp0; lL[prow1] = lp1; }
  } else {
    PV_BODY(NCH);
  }
  __syncthreads();

  // ---- epilogue: PV waves write out = gamma*O/l + x ----
  if (!isS) {
    const float g = gamma[0];
#pragma unroll
    for (int isub = 0; isub < 4; ++isub) {
#pragma unroll
      for (int q = 0; q < 4; ++q) {
        const int r0 = isub * 32 + q * 8 + l5 * 4;   // D row: (reg&3)+8q+4*l5
        const f32x4 li = *(const f32x4*)&lL[r0];
        f32x4 gi;
#pragma unroll
        for (int r = 0; r < 4; ++r) gi[r] = g / li[r];
        {
          const int c = p * 64 + c32;
          const size_t base = ((size_t)(b * NC + c)) * NN + i0 + r0;
          const f32x4 xv = *(const f32x4*)(x + base);
          f32x4 ov;
#pragma unroll
          for (int r = 0; r < 4; ++r) ov[r] = OA[isub][q * 4 + r] * gi[r] + xv[r];
          *(f32x4*)(out + base) = ov;
        }
        {
          const int c = p * 64 + 32 + c32;
          const size_t base = ((size_t)(b * NC + c)) * NN + i0 + r0;
          const f32x4 xv = *(const f32x4*)(x + base);
          f32x4 ov;
#pragma unroll
          for (int r = 0; r < 4; ++r) ov[r] = OB[isub][q * 4 + r] * gi[r] + xv[r];
          *(f32x4*)(out + base) = ov;
        }
      }
    }
  }
}

extern "C" void kernel_launch(void* const* d_in, const int* in_sizes, int n_in,
                              void* d_out, int out_size, void* d_ws, size_t ws_size,
                              hipStream_t stream) {
  const float* x  = (const float*)d_in[0];
  const float* wq = (const float*)d_in[1];
  const float* bq = (const float*)d_in[2];
  const float* wk = (const float*)d_in[3];
  const float* bk = (const float*)d_in[4];
  const float* wv = (const float*)d_in[5];
  const float* bv = (const float*)d_in[6];
  const float* gm = (const float*)d_in[7];
  float* outp = (float*)d_out;

  ushort* qkw = (ushort*)d_ws;                       // [B][N][64]  bf16, 4 MB
  ushort* vtw = qkw + (size_t)NB * NN * 64;          // [B][C][N]   bf16, 16 MB

  proj_kernel<<<dim3(NN / 128, 5, NB), 256, 0, stream>>>(
      x, wq, bq, wk, bk, wv, bv, qkw, vtw);
  attn_kernel<<<dim3((NN / 128) * NB), 512, 0, stream>>>(qkw, vtw, x, gm, outp);
}

// Round 13
// 247.546 us; speedup vs baseline: 1.3776x; 1.3776x over previous
//
#include <hip/hip_runtime.h>
#include <hip/hip_bf16.h>

typedef __attribute__((ext_vector_type(8))) short short8;   // 8 bf16 (4 VGPRs)
typedef __attribute__((ext_vector_type(4))) float f32x4;    // MFMA 16x16 C/D
typedef __attribute__((ext_vector_type(16))) float f32x16;  // MFMA 32x32 C/D

#define NB 8
#define NC 256
#define NN 4096
#define ND 32
#define NCH 16   // j-chunks of 256
#define LOG2E 1.44269504088896340736f

// P tile [2][128][256] ushort, 16B-slot XOR swizzle (validated R8/R10).
#define PIDX(row, col) (((row) << 8) + ((col) ^ (((row) & 15) << 3)))

static __device__ __forceinline__ ushort f2bf(float f) {
  __hip_bfloat16 h = __float2bfloat16(f);
  return reinterpret_cast<ushort&>(h);
}

// ---------------------------------------------------------------------------
// Projection (unchanged): fp32 MAC, bf16 out; Q pre-scaled by log2(e).
//   blockIdx.y==0 : o in [0,64)  -> QK[b][n][64]  (q 0..31, k 32..63)
//   blockIdx.y>=1 : o in [64,320)-> Vt[b][o-64][n]  (V transposed, bf16)
// ---------------------------------------------------------------------------
__global__ __launch_bounds__(256, 4)
void proj_kernel(const float* __restrict__ x,
                 const float* __restrict__ wq, const float* __restrict__ bq,
                 const float* __restrict__ wk, const float* __restrict__ bk,
                 const float* __restrict__ wv, const float* __restrict__ bv,
                 ushort* __restrict__ qk, ushort* __restrict__ vt) {
  __shared__ float Xs[16][128];
  __shared__ float Ws[16][64];
  const int n0 = blockIdx.x * 128;
  const int o0 = blockIdx.y * 64;
  const int b  = blockIdx.z;
  const int t  = threadIdx.x;
  const int og4 = t & 15;
  const int ng  = t >> 4;

  float acc[4][8];
#pragma unroll
  for (int i = 0; i < 4; ++i)
#pragma unroll
    for (int j = 0; j < 8; ++j) acc[i][j] = 0.f;

  const int xs_r = t >> 4;
  const int xs_c = (t & 15) * 4;
  const int ws_o = t & 63;
  const int ws_c = (t >> 6) * 4;
  const float* wrow;
  {
    const int o = o0 + ws_o;
    if (o < 32)      wrow = wq + (size_t)o * NC;
    else if (o < 64) wrow = wk + (size_t)(o - 32) * NC;
    else             wrow = wv + (size_t)(o - 64) * NC;
  }

  for (int c0 = 0; c0 < NC; c0 += 16) {
    __syncthreads();
    const float* xsrc = x + ((size_t)(b * NC + c0 + xs_r)) * NN + n0;
    *(float4*)&Xs[xs_r][xs_c]      = *(const float4*)(xsrc + xs_c);
    *(float4*)&Xs[xs_r][64 + xs_c] = *(const float4*)(xsrc + 64 + xs_c);
    {
      const float4 wv4 = *(const float4*)(wrow + c0 + ws_c);
      Ws[ws_c + 0][ws_o] = wv4.x;
      Ws[ws_c + 1][ws_o] = wv4.y;
      Ws[ws_c + 2][ws_o] = wv4.z;
      Ws[ws_c + 3][ws_o] = wv4.w;
    }
    __syncthreads();
#pragma unroll
    for (int cc = 0; cc < 16; ++cc) {
      const float4 wv4 = *(const float4*)&Ws[cc][og4 * 4];
      const float4 xa  = *(const float4*)&Xs[cc][ng * 8];
      const float4 xb  = *(const float4*)&Xs[cc][ng * 8 + 4];
      const float wvv[4] = {wv4.x, wv4.y, wv4.z, wv4.w};
      const float xaa[8] = {xa.x, xa.y, xa.z, xa.w, xb.x, xb.y, xb.z, xb.w};
#pragma unroll
      for (int i = 0; i < 4; ++i)
#pragma unroll
        for (int j = 0; j < 8; ++j) acc[i][j] += wvv[i] * xaa[j];
    }
  }

  if (blockIdx.y == 0) {
    float bb[4], sc[4];
#pragma unroll
    for (int i = 0; i < 4; ++i) {
      const int o = og4 * 4 + i;
      bb[i] = (o < 32) ? bq[o] : bk[o - 32];
      sc[i] = (o < 32) ? LOG2E : 1.0f;
    }
#pragma unroll
    for (int j = 0; j < 8; ++j) {
      union { ushort u[4]; uint2 v; } pk;
#pragma unroll
      for (int i = 0; i < 4; ++i) pk.u[i] = f2bf((acc[i][j] + bb[i]) * sc[i]);
      *(uint2*)(qk + ((size_t)(b * NN + n0 + ng * 8 + j)) * 64 + og4 * 4) = pk.v;
    }
  } else {
#pragma unroll
    for (int i = 0; i < 4; ++i) {
      const int c = o0 - 64 + og4 * 4 + i;
      const float bb = bv[c];
      union { ushort u[8]; uint4 v; } pk;
#pragma unroll
      for (int j = 0; j < 8; ++j) pk.u[j] = f2bf(acc[i][j] + bb);
      *(uint4*)(vt + ((size_t)(b * NC + c)) * NN + n0 + ng * 8) = pk.v;
    }
  }
}

// ---------------------------------------------------------------------------
// Flash attention, UNIFIED waves + cross-phase prefetch.
// 256 blocks x 512 threads (8 waves). Block = (b, 128 q-rows). j-chunk 256,
// 16 intervals, ONE barrier each. P dbuf [2][128][256] swizzled (128 KB).
// Per interval, each wave:
//   S(c): [issue K half1(c)] [compute half0 from kfA: swapped mfma16(K,Q),
//         exp2, trunc-bf16 pack, b64 P writes] [compute half1 from kfB]
//         [issue V groups 0,1 of chunk c]  -> barrier
//   PV(c): [issue K half0(c+1) into kfA] 64 mfma32 over its 64-row x 64-ch
//         tile (rg=w>>2, cg=w&3), A=P from LDS, B=V 3-buffer rotation
//         2 groups ahead (~220cyc >= L2 latency).
// Registers: kfA 32 + kfB 32 + qf 4 + V 48 + O 64 AGPR + temps ~ 214 < 256
// (2 waves/SIMD pool) -> no spill, unlike R12's 320-reg role-split frame.
// ---------------------------------------------------------------------------
#define MFMA32(A, B, C) __builtin_amdgcn_mfma_f32_32x32x16_bf16(A, B, C, 0, 0, 0)

// One S sub-step: 1 mfma16 + 4 exp2 + trunc-pack + b64 write.
#define S_JT(KF, COL)                                                         \
  do {                                                                        \
    const f32x4 s = __builtin_amdgcn_mfma_f32_16x16x32_bf16(KF, qf, zero,     \
                                                            0, 0, 0);         \
    const uint t0 = __builtin_bit_cast(uint, exp2f(s[0])) & 0xFFFF0000u;      \
    const uint t1 = __builtin_bit_cast(uint, exp2f(s[1])) & 0xFFFF0000u;      \
    const uint t2 = __builtin_bit_cast(uint, exp2f(s[2])) & 0xFFFF0000u;      \
    const uint t3 = __builtin_bit_cast(uint, exp2f(s[3])) & 0xFFFF0000u;      \
    lp += (__builtin_bit_cast(float, t0) + __builtin_bit_cast(float, t1)) +   \
          (__builtin_bit_cast(float, t2) + __builtin_bit_cast(float, t3));    \
    uint2 wv;                                                                 \
    wv.x = (t0 >> 16) | t1;                                                   \
    wv.y = (t2 >> 16) | t3;                                                   \
    *(uint2*)&Pb[PIDX(prow, (COL) + g16 * 4)] = wv;                           \
  } while (0)

#define V_LOAD(S0, S1, S2, S3, J0, G)                                         \
  do {                                                                        \
    S0 = *(const short8*)(vbA + (J0) + (G) * 32);                             \
    S1 = *(const short8*)(vbB + (J0) + (G) * 32);                             \
    S2 = *(const short8*)(vbA + (J0) + (G) * 32 + 16);                        \
    S3 = *(const short8*)(vbB + (J0) + (G) * 32 + 16);                        \
  } while (0)

#define V_COMP(S0, S1, S2, S3, G)                                             \
  do {                                                                        \
    const int joA = (G) * 32;                                                 \
    const short8 pa0 = *(const short8*)&Pb[PIDX(prA, joA + l5 * 8)];          \
    const short8 pa1 = *(const short8*)&Pb[PIDX(prB, joA + l5 * 8)];          \
    O00 = MFMA32(pa0, S0, O00);  O01 = MFMA32(pa0, S1, O01);                  \
    O10 = MFMA32(pa1, S0, O10);  O11 = MFMA32(pa1, S1, O11);                  \
    const short8 pb0 = *(const short8*)&Pb[PIDX(prA, joA + 16 + l5 * 8)];     \
    const short8 pb1 = *(const short8*)&Pb[PIDX(prB, joA + 16 + l5 * 8)];     \
    O00 = MFMA32(pb0, S2, O00);  O01 = MFMA32(pb0, S3, O01);                  \
    O10 = MFMA32(pb1, S2, O10);  O11 = MFMA32(pb1, S3, O11);                  \
  } while (0)

__global__ __launch_bounds__(512, 1)
void attn_kernel(const ushort* __restrict__ qk, const ushort* __restrict__ vt,
                 const float* __restrict__ x, const float* __restrict__ gamma,
                 float* __restrict__ out) {
  __shared__ __align__(16) ushort P[2][128 * 256];   // 128 KB, swizzled
  __shared__ __align__(16) float lL[128];

  const int lin  = blockIdx.x;
  const int b    = lin & 7;              // XCD swizzle: batch per XCD L2
  const int i0   = (lin >> 3) * 128;
  const int t    = threadIdx.x;
  const int w    = t >> 6;               // 0..7
  const int lane = t & 63;
  const int g16  = lane >> 4;
  const int c16  = lane & 15;
  const int l5   = lane >> 5;
  const int c32  = lane & 31;
  const int rg   = w >> 2;               // PV row-group (0..1): rows rg*64..+64
  const int cg   = w & 3;                // PV col-group (0..3): ch cg*64..+64

  const f32x4 zero = {0.f, 0.f, 0.f, 0.f};

  // S state: wave w owns q-rows w*16..+16
  const int prow = w * 16 + c16;
  const short8 qf = *(const short8*)(
      qk + ((size_t)(b * NN + i0 + prow)) * 64 + g16 * 8);
  float lp = 0.f;
  const ushort* kbase = qk + ((size_t)b * NN) * 64 + 32 + g16 * 8;

  // PV state
  const int prA = rg * 64 + c32;         // P row for isub 0
  const int prB = prA + 32;              // P row for isub 1
  const ushort* vbA = vt + ((size_t)(b * NC + cg * 64 + c32)) * NN + l5 * 8;
  const ushort* vbB = vbA + (size_t)32 * NN;
  f32x16 O00, O01, O10, O11;
#pragma unroll
  for (int e = 0; e < 16; ++e) { O00[e] = 0.f; O01[e] = 0.f; O10[e] = 0.f; O11[e] = 0.f; }

  short8 kfA0, kfA1, kfA2, kfA3, kfA4, kfA5, kfA6, kfA7;
  short8 kfB0, kfB1, kfB2, kfB3, kfB4, kfB5, kfB6, kfB7;
  short8 v00, v01, v02, v03, v10, v11, v12, v13, v20, v21, v22, v23;

#define KLOAD_A(J0)                                                           \
  do {                                                                        \
    kfA0 = *(const short8*)(kbase + (size_t)((J0) + 0 * 16 + c16) * 64);      \
    kfA1 = *(const short8*)(kbase + (size_t)((J0) + 1 * 16 + c16) * 64);      \
    kfA2 = *(const short8*)(kbase + (size_t)((J0) + 2 * 16 + c16) * 64);      \
    kfA3 = *(const short8*)(kbase + (size_t)((J0) + 3 * 16 + c16) * 64);      \
    kfA4 = *(const short8*)(kbase + (size_t)((J0) + 4 * 16 + c16) * 64);      \
    kfA5 = *(const short8*)(kbase + (size_t)((J0) + 5 * 16 + c16) * 64);      \
    kfA6 = *(const short8*)(kbase + (size_t)((J0) + 6 * 16 + c16) * 64);      \
    kfA7 = *(const short8*)(kbase + (size_t)((J0) + 7 * 16 + c16) * 64);      \
  } while (0)
#define KLOAD_B(J0)                                                           \
  do {                                                                        \
    kfB0 = *(const short8*)(kbase + (size_t)((J0) + 0 * 16 + c16) * 64);      \
    kfB1 = *(const short8*)(kbase + (size_t)((J0) + 1 * 16 + c16) * 64);      \
    kfB2 = *(const short8*)(kbase + (size_t)((J0) + 2 * 16 + c16) * 64);      \
    kfB3 = *(const short8*)(kbase + (size_t)((J0) + 3 * 16 + c16) * 64);      \
    kfB4 = *(const short8*)(kbase + (size_t)((J0) + 4 * 16 + c16) * 64);      \
    kfB5 = *(const short8*)(kbase + (size_t)((J0) + 5 * 16 + c16) * 64);      \
    kfB6 = *(const short8*)(kbase + (size_t)((J0) + 6 * 16 + c16) * 64);      \
    kfB7 = *(const short8*)(kbase + (size_t)((J0) + 7 * 16 + c16) * 64);      \
  } while (0)

  // prologue: K half0 of chunk 0
  KLOAD_A(0);

  for (int c = 0; c < NCH; ++c) {
    const int j0 = c * 256;
    ushort* Pb = &P[c & 1][0];

    // ---- S(c): issue half1, compute half0 (kfA), compute half1 (kfB) ----
    KLOAD_B(j0 + 128);
    S_JT(kfA0, 0);   S_JT(kfA1, 16);  S_JT(kfA2, 32);  S_JT(kfA3, 48);
    S_JT(kfA4, 64);  S_JT(kfA5, 80);  S_JT(kfA6, 96);  S_JT(kfA7, 112);
    S_JT(kfB0, 128); S_JT(kfB1, 144); S_JT(kfB2, 160); S_JT(kfB3, 176);
    S_JT(kfB4, 192); S_JT(kfB5, 208); S_JT(kfB6, 224); S_JT(kfB7, 240);

    // early V for PV(c): groups 0,1 issued before the barrier
    V_LOAD(v00, v01, v02, v03, j0, 0);
    V_LOAD(v10, v11, v12, v13, j0, 1);

    __syncthreads();   // P[c&1] complete; PV(c) may read it

    // ---- PV(c): prefetch K half0(c+1); V 3-buffer rotation, 64 mfma32 ----
    if (c + 1 < NCH) KLOAD_A(j0 + 256);

    __builtin_amdgcn_s_setprio(1);
    V_LOAD(v20, v21, v22, v23, j0, 2);  V_COMP(v00, v01, v02, v03, 0);
    V_LOAD(v00, v01, v02, v03, j0, 3);  V_COMP(v10, v11, v12, v13, 1);
    V_LOAD(v10, v11, v12, v13, j0, 4);  V_COMP(v20, v21, v22, v23, 2);
    V_LOAD(v20, v21, v22, v23, j0, 5);  V_COMP(v00, v01, v02, v03, 3);
    V_LOAD(v00, v01, v02, v03, j0, 6);  V_COMP(v10, v11, v12, v13, 4);
    V_LOAD(v10, v11, v12, v13, j0, 7);  V_COMP(v20, v21, v22, v23, 5);
    V_COMP(v00, v01, v02, v03, 6);      V_COMP(v10, v11, v12, v13, 7);
    __builtin_amdgcn_s_setprio(0);
    // no second barrier: S(c+1) writes P[(c+1)&1]; S(c+2) (which overwrites
    // P[c&1]) is fenced by the barrier inside interval c+1.
  }

  // ---- final l per q-row: reduce over the 4 g16 lane-groups ----
  lp += __shfl_xor(lp, 16);
  lp += __shfl_xor(lp, 32);
  if (g16 == 0) lL[prow] = lp;
  __syncthreads();

  // ---- epilogue: out = gamma*O/l + x ----
  const float g = gamma[0];
#define EPI_TILE(OT, ISUB, CHOFF)                                             \
  do {                                                                        \
    _Pragma("unroll")                                                         \
    for (int q = 0; q < 4; ++q) {                                             \
      const int r0 = rg * 64 + (ISUB) * 32 + q * 8 + l5 * 4;                  \
      const f32x4 li = *(const f32x4*)&lL[r0];                                \
      f32x4 gi;                                                               \
      _Pragma("unroll")                                                       \
      for (int r = 0; r < 4; ++r) gi[r] = g / li[r];                          \
      const int ch = cg * 64 + (CHOFF) + c32;                                 \
      const size_t base = ((size_t)(b * NC + ch)) * NN + i0 + r0;             \
      const f32x4 xv = *(const f32x4*)(x + base);                             \
      f32x4 ov;                                                               \
      _Pragma("unroll")                                                       \
      for (int r = 0; r < 4; ++r) ov[r] = OT[q * 4 + r] * gi[r] + xv[r];      \
      *(f32x4*)(out + base) = ov;                                             \
    }                                                                         \
  } while (0)
  EPI_TILE(O00, 0, 0);
  EPI_TILE(O01, 0, 32);
  EPI_TILE(O10, 1, 0);
  EPI_TILE(O11, 1, 32);
}

extern "C" void kernel_launch(void* const* d_in, const int* in_sizes, int n_in,
                              void* d_out, int out_size, void* d_ws, size_t ws_size,
                              hipStream_t stream) {
  const float* x  = (const float*)d_in[0];
  const float* wq = (const float*)d_in[1];
  const float* bq = (const float*)d_in[2];
  const float* wk = (const float*)d_in[3];
  const float* bk = (const float*)d_in[4];
  const float* wv = (const float*)d_in[5];
  const float* bv = (const float*)d_in[6];
  const float* gm = (const float*)d_in[7];
  float* outp = (float*)d_out;

  ushort* qkw = (ushort*)d_ws;                       // [B][N][64]  bf16, 4 MB
  ushort* vtw = qkw + (size_t)NB * NN * 64;          // [B][C][N]   bf16, 16 MB

  proj_kernel<<<dim3(NN / 128, 5, NB), 256, 0, stream>>>(
      x, wq, bq, wk, bk, wv, bv, qkw, vtw);
  attn_kernel<<<dim3((NN / 128) * NB), 512, 0, stream>>>(qkw, vtw, x, gm, outp);
}